// Round 9
// baseline (437.479 us; speedup 1.0000x reference)
//
#include <hip/hip_runtime.h>

// Problem: B=32, LQ=1024, LKV=1024, D=512, fp32.
// out = [output (B*LQ*D), attn (B*LQ*LKV)] concatenated, fp32.

constexpr int NB  = 32;
constexpr int LQ  = 1024;
constexpr int LKV = 1024;
constexpr int DD  = 512;
constexpr int NROWS = NB * LQ;   // 32768 score rows

typedef __attribute__((ext_vector_type(4))) float f4;
typedef __attribute__((ext_vector_type(4))) float f32x4;
typedef __attribute__((ext_vector_type(4))) unsigned short u16x4;
typedef __attribute__((ext_vector_type(8))) __bf16 bf16x8;

__device__ __forceinline__ unsigned short f2bf(float x) {
  unsigned u = __builtin_bit_cast(unsigned, x);
  unsigned r = u + 0x7FFFu + ((u >> 16) & 1u);   // round-to-nearest-even
  return (unsigned short)(r >> 16);
}
__device__ __forceinline__ float bf2f(unsigned short h) {
  unsigned u = ((unsigned)h) << 16;
  return __builtin_bit_cast(float, u);
}

__device__ __forceinline__ void gload16(const void* g, void* l) {
  __builtin_amdgcn_global_load_lds((const __attribute__((address_space(1))) unsigned int*)g,
                                   (__attribute__((address_space(3))) unsigned int*)l,
                                   16, 0, 0);
}

constexpr int PAD = 40;

// ---------------------------------------------------------------------------
// Prep (merged): Q -> Qh,Ql ; KV -> Kh,Kl ([kv][d]) and KVT ([d][kv], hi only)
// ---------------------------------------------------------------------------
__global__ __launch_bounds__(256) void prep_all_kernel(const float* __restrict__ Q,
                                                       const float* __restrict__ KV,
                                                       unsigned short* __restrict__ Qh,
                                                       unsigned short* __restrict__ Ql,
                                                       unsigned short* __restrict__ Kh,
                                                       unsigned short* __restrict__ Kl,
                                                       unsigned short* __restrict__ KVT)
{
  __shared__ unsigned short T[64][72];
  const int b  = blockIdx.z;
  const int tk = blockIdx.y;   // lq/kv tile (64), 0..15
  const int td = blockIdx.x;   // d tile (64), 0..7
  const int tid = threadIdx.x;

#pragma unroll
  for (int i = 0; i < 4; ++i) {
    int idx = tid + i * 256;
    int r   = idx >> 4;
    int c4  = (idx & 15) << 2;
    size_t goff = ((size_t)b * LKV + tk * 64 + r) * DD + td * 64 + c4;
    f4 v = *(const f4*)(KV + goff);
    u16x4 h, l;
#pragma unroll
    for (int u = 0; u < 4; ++u) {
      h[u] = f2bf(v[u]);
      l[u] = f2bf(v[u] - bf2f(h[u]));
    }
    *(u16x4*)&T[r][c4] = h;
    *(u16x4*)(Kh + goff) = h;
    *(u16x4*)(Kl + goff) = l;

    f4 q = *(const f4*)(Q + goff);
    u16x4 qh, ql;
#pragma unroll
    for (int u = 0; u < 4; ++u) {
      qh[u] = f2bf(q[u]);
      ql[u] = f2bf(q[u] - bf2f(qh[u]));
    }
    *(u16x4*)(Qh + goff) = qh;
    *(u16x4*)(Ql + goff) = ql;
  }
  __syncthreads();

#pragma unroll
  for (int i = 0; i < 4; ++i) {
    int idx = tid + i * 256;
    int c   = idx >> 4;                 // d row 0..63
    int r4  = (idx & 15) << 2;          // kv col
    u16x4 w = { T[r4][c], T[r4 + 1][c], T[r4 + 2][c], T[r4 + 3][c] };
    *(u16x4*)(KVT + ((size_t)b * DD + td * 64 + c) * LKV + tk * 64 + r4) = w;
  }
}

// ---------------------------------------------------------------------------
// Kernel 1 (new): S = Q@KV^T (split-bf16, 3 MFMA) + partial softmax stats.
// LDS-FREE: each wave loads its MFMA fragments DIRECTLY from global (L2-hot
// via XCD swizzle, proven 65MB FETCH in round 8). No barriers, no staging,
// no LDS -> waves fully independent; compiler pipelines load->MFMA freely.
// Per-block duplication is only 2x (A read by 2 col-waves, B by 2 row-waves).
// ---------------------------------------------------------------------------
__global__ __launch_bounds__(256, 3) void gemm_qk8_kernel(const unsigned short* __restrict__ Qh,
                                                          const unsigned short* __restrict__ Ql,
                                                          const unsigned short* __restrict__ Kh,
                                                          const unsigned short* __restrict__ Kl,
                                                          float* __restrict__ S,
                                                          float* __restrict__ Pmax,
                                                          float* __restrict__ Psum)
{
  // XCD swizzle (bijective, nwg=2048 %8==0): each XCD gets a contiguous
  // logical range -> Q/K panels L2-resident per XCD.
  const int n       = blockIdx.x;              // 0..2047
  const int logical = (n & 7) * 256 + (n >> 3);
  const int b   = logical >> 6;
  const int t   = logical & 63;
  const int ti  = t >> 3;
  const int tj  = t & 7;
  const int tid  = threadIdx.x;
  const int lane = tid & 63;
  const int wid  = tid >> 6;            // 0..3
  const int wr = (wid >> 1) * 64;
  const int wc = (wid & 1) * 64;

  const size_t qo = ((size_t)b * LQ  + ti * 128) * DD;
  const size_t ko = ((size_t)b * LKV + tj * 128) * DD;
  const unsigned short* Aq = Qh + qo;
  const unsigned short* Al_ = Ql + qo;
  const unsigned short* Bh_ = Kh + ko;
  const unsigned short* Bl_ = Kl + ko;

  const int l15 = lane & 15;
  const int kf0 = (lane >> 4) << 3;      // 0,8,16,24 within k32

  // per-fragment row offsets (elements), constant over the K loop
  int rowA[4], rowB[4];
#pragma unroll
  for (int m = 0; m < 4; ++m) rowA[m] = (wr + m * 16 + l15) * DD + kf0;
#pragma unroll
  for (int nn = 0; nn < 4; ++nn) rowB[nn] = (wc + nn * 16 + l15) * DD + kf0;

  f32x4 acc[4][4] = {};

#pragma unroll 2
  for (int ks = 0; ks < DD; ks += 32) {
    bf16x8 ah[4], al[4], bh[4], bl[4];
#pragma unroll
    for (int m = 0; m < 4; ++m) {
      ah[m] = *(const bf16x8*)(Aq  + rowA[m] + ks);
      al[m] = *(const bf16x8*)(Al_ + rowA[m] + ks);
    }
#pragma unroll
    for (int nn = 0; nn < 4; ++nn) {
      bh[nn] = *(const bf16x8*)(Bh_ + rowB[nn] + ks);
      bl[nn] = *(const bf16x8*)(Bl_ + rowB[nn] + ks);
    }
#pragma unroll
    for (int m = 0; m < 4; ++m)
#pragma unroll
      for (int nn = 0; nn < 4; ++nn)
        acc[m][nn] = __builtin_amdgcn_mfma_f32_16x16x32_bf16(ah[m], bh[nn], acc[m][nn], 0, 0, 0);
#pragma unroll
    for (int m = 0; m < 4; ++m)
#pragma unroll
      for (int nn = 0; nn < 4; ++nn)
        acc[m][nn] = __builtin_amdgcn_mfma_f32_16x16x32_bf16(ah[m], bl[nn], acc[m][nn], 0, 0, 0);
#pragma unroll
    for (int m = 0; m < 4; ++m)
#pragma unroll
      for (int nn = 0; nn < 4; ++nn)
        acc[m][nn] = __builtin_amdgcn_mfma_f32_16x16x32_bf16(al[m], bh[nn], acc[m][nn], 0, 0, 0);
  }

  // ---- store raw scores ----
  float* Sb = S + (size_t)b * LQ * LKV;
#pragma unroll
  for (int m = 0; m < 4; ++m) {
    int row0 = ti * 128 + wr + m * 16 + ((lane >> 4) << 2);
#pragma unroll
    for (int nn = 0; nn < 4; ++nn) {
      int col = tj * 128 + wc + nn * 16 + (lane & 15);
#pragma unroll
      for (int j = 0; j < 4; ++j)
        Sb[(size_t)(row0 + j) * LKV + col] = acc[m][nn][j];
    }
  }

  // ---- per-row partial stats over this wave's 64 cols ----
  const int g16  = lane >> 4;
  const int l16  = lane & 15;
  const int wcid = wc >> 6;   // 0 or 1
#pragma unroll
  for (int m = 0; m < 4; ++m) {
#pragma unroll
    for (int j = 0; j < 4; ++j) {
      float rm = fmaxf(fmaxf(acc[m][0][j], acc[m][1][j]), fmaxf(acc[m][2][j], acc[m][3][j]));
#pragma unroll
      for (int off = 8; off >= 1; off >>= 1)
        rm = fmaxf(rm, __shfl_xor(rm, off));
      float se = 0.f;
#pragma unroll
      for (int nn = 0; nn < 4; ++nn)
        se += __expf(acc[m][nn][j] - rm);
#pragma unroll
      for (int off = 8; off >= 1; off >>= 1)
        se += __shfl_xor(se, off);
      if (l16 == 0) {
        int row  = ti * 128 + wr + m * 16 + g16 * 4 + j;
        size_t p = ((size_t)b * LQ + row) * 16 + tj * 2 + wcid;
        Pmax[p] = rm;
        Psum[p] = se;
      }
    }
  }
}

// ---------------------------------------------------------------------------
// Reduce: 16 partials/row -> M[row], Inv[row] = 1/sum
// ---------------------------------------------------------------------------
__global__ __launch_bounds__(256) void reduce_stats_kernel(const float* __restrict__ Pmax,
                                                           const float* __restrict__ Psum,
                                                           float* __restrict__ M,
                                                           float* __restrict__ Inv)
{
  int row = blockIdx.x * 256 + threadIdx.x;
  const float* pm = Pmax + (size_t)row * 16;
  const float* ps = Psum + (size_t)row * 16;
  float mx = pm[0];
#pragma unroll
  for (int i = 1; i < 16; ++i) mx = fmaxf(mx, pm[i]);
  float s = 0.f;
#pragma unroll
  for (int i = 0; i < 16; ++i) s += ps[i] * __expf(pm[i] - mx);
  M[row]   = mx;
  Inv[row] = 1.0f / s;
}

// ---------------------------------------------------------------------------
// Kernel 3: fused normalize + O = softmax(S) @ KV.
// BM=128, BN=512, BK=64, 1024 threads = 16 waves (4x4). XCD swizzle.
// ---------------------------------------------------------------------------
__global__ __launch_bounds__(1024, 4) void gemm_av7_kernel(float* __restrict__ Sio,
                                                           const unsigned short* __restrict__ KVT,
                                                           const float* __restrict__ Mrow,
                                                           const float* __restrict__ Invr,
                                                           float* __restrict__ O)
{
  __shared__ unsigned short Asm[128][72];      // 18 KB padded
  __shared__ unsigned short Bsm[512 * 64];     // 64 KB linear, chunk-swizzled
  __shared__ float Ms[128], Is[128];
  // XCD swizzle over flattened 256-block grid (8 mi x 32 b).
  const int n       = blockIdx.x;              // 0..255
  const int logical = (n & 7) * 32 + (n >> 3);
  const int b  = logical >> 3;
  const int mi = logical & 7;
  const int tid  = threadIdx.x;       // 0..1023
  const int lane = tid & 63;
  const int wid  = tid >> 6;          // 0..15
  const int wr  = (wid >> 2) * 32;    // wave row base: 0,32,64,96
  const int wcb = (wid & 3) * 128;    // wave col base: 0,128,256,384

  float* Sb = Sio + ((size_t)b * LQ + mi * 128) * LKV;
  const unsigned short* Bb = KVT + (size_t)b * DD * LKV;

  if (tid < 128) {
    int gr = b * LQ + mi * 128 + tid;
    Ms[tid] = Mrow[gr];
    Is[tid] = Invr[gr];
  }

  const int lr8 = lane >> 3;
  const int ssw = (lane & 7) ^ lr8;    // pre-swizzled global slot for staging

  f32x4 acc[2][8] = {};

  for (int ks = 0; ks < LKV; ks += 64) {
    __syncthreads();   // first iter also publishes Ms/Is
    // ---- A: 128 x 64 raw S -> p=exp(s-M)*Inv -> attn (in place) + bf16 LDS
#pragma unroll
    for (int i = 0; i < 2; ++i) {
      int idx = tid + i * 1024;        // 0..2047
      int r   = idx >> 4;              // 0..127
      int k4  = (idx & 15) << 2;       // 0,4,..,60
      float* ap = Sb + (size_t)r * LKV + ks + k4;
      f4 v = *(const f4*)ap;
      float mr = Ms[r], ir = Is[r];
      f4 p; u16x4 h;
#pragma unroll
      for (int u = 0; u < 4; ++u) {
        p[u] = __expf(v[u] - mr) * ir;
        h[u] = f2bf(p[u]);
      }
      *(f4*)ap = p;
      *(u16x4*)&Asm[r][k4] = h;
    }
    // ---- B: 512 d-rows x 64 kv via gload_lds (4 chunks/wave, 64 total) ----
#pragma unroll
    for (int c = 0; c < 4; ++c) {
      int cc = wid * 4 + c;                    // 0..63
      int dd = cc * 8 + lr8;                   // 0..511
      const unsigned short* g = Bb + (size_t)dd * LKV + ks + ssw * 8;
      gload16(g, &Bsm[cc * 512]);
    }
    __syncthreads();

    // ---- compute: 2 k-subtiles of 32 ----
#pragma unroll
    for (int kk = 0; kk < 64; kk += 32) {
      const int kf = kk + ((lane >> 4) << 3);
      const int cl = kf >> 3;
      bf16x8 af[2];
#pragma unroll
      for (int m = 0; m < 2; ++m)
        af[m] = *(const bf16x8*)&Asm[wr + m * 16 + (lane & 15)][kf];
#pragma unroll
      for (int h = 0; h < 2; ++h) {
        bf16x8 bfv[4];
#pragma unroll
        for (int nn = 0; nn < 4; ++nn) {
          int dd = wcb + (h * 4 + nn) * 16 + (lane & 15);
          int sp = cl ^ (dd & 7);
          bfv[nn] = *(const bf16x8*)&Bsm[dd * 64 + sp * 8];
        }
#pragma unroll
        for (int m = 0; m < 2; ++m)
#pragma unroll
          for (int nn = 0; nn < 4; ++nn)
            acc[m][h * 4 + nn] =
                __builtin_amdgcn_mfma_f32_16x16x32_bf16(af[m], bfv[nn], acc[m][h * 4 + nn], 0, 0, 0);
      }
    }
  }

  float* Ob = O + ((size_t)b * LQ + mi * 128) * DD;
#pragma unroll
  for (int m = 0; m < 2; ++m) {
    int r0 = wr + m * 16 + ((lane >> 4) << 2);
#pragma unroll
    for (int nn = 0; nn < 8; ++nn) {
      int col = wcb + nn * 16 + (lane & 15);
#pragma unroll
      for (int j = 0; j < 4; ++j)
        Ob[(size_t)(r0 + j) * DD + col] = acc[m][nn][j];
    }
  }
}

// ===========================================================================
// Fallback kernels (smaller ws paths) — unchanged.
// ===========================================================================
__global__ __launch_bounds__(256) void gemm_qk_kernel(const float* __restrict__ Q,
                                                      const float* __restrict__ KV,
                                                      float* __restrict__ S)
{
  __shared__ unsigned short Ah[128][PAD], Al[128][PAD], Bh[128][PAD], Bl[128][PAD];
  const int b   = blockIdx.y;
  const int ti  = blockIdx.x >> 3;
  const int tj  = blockIdx.x & 7;
  const int tid  = threadIdx.x;
  const int lane = tid & 63;
  const int wid  = tid >> 6;
  const int wr = (wid >> 1) * 64;
  const int wc = (wid & 1) * 64;

  const float* Qb = Q  + (size_t)b * LQ  * DD + (size_t)ti * 128 * DD;
  const float* Kb = KV + (size_t)b * LKV * DD + (size_t)tj * 128 * DD;

  f32x4 acc[4][4] = {};

  for (int ks = 0; ks < DD; ks += 32) {
    __syncthreads();
#pragma unroll
    for (int i = 0; i < 4; ++i) {
      int idx = tid + i * 256;
      int r   = idx >> 3;
      int k4  = (idx & 7) << 2;
      f4 qa = *(const f4*)(Qb + (size_t)r * DD + ks + k4);
      f4 ka = *(const f4*)(Kb + (size_t)r * DD + ks + k4);
      u16x4 qh, ql, kh, kl;
#pragma unroll
      for (int u = 0; u < 4; ++u) {
        unsigned short h = f2bf(qa[u]);
        qh[u] = h;  ql[u] = f2bf(qa[u] - bf2f(h));
        unsigned short h2 = f2bf(ka[u]);
        kh[u] = h2; kl[u] = f2bf(ka[u] - bf2f(h2));
      }
      *(u16x4*)&Ah[r][k4] = qh;  *(u16x4*)&Al[r][k4] = ql;
      *(u16x4*)&Bh[r][k4] = kh;  *(u16x4*)&Bl[r][k4] = kl;
    }
    __syncthreads();

    const int kf = (lane >> 4) << 3;
    bf16x8 ah[4], al[4], bh[4], bl[4];
#pragma unroll
    for (int m = 0; m < 4; ++m) {
      int row = wr + m * 16 + (lane & 15);
      ah[m] = *(const bf16x8*)&Ah[row][kf];
      al[m] = *(const bf16x8*)&Al[row][kf];
    }
#pragma unroll
    for (int n = 0; n < 4; ++n) {
      int row = wc + n * 16 + (lane & 15);
      bh[n] = *(const bf16x8*)&Bh[row][kf];
      bl[n] = *(const bf16x8*)&Bl[row][kf];
    }
#pragma unroll
    for (int m = 0; m < 4; ++m)
#pragma unroll
      for (int n = 0; n < 4; ++n) {
        acc[m][n] = __builtin_amdgcn_mfma_f32_16x16x32_bf16(ah[m], bh[n], acc[m][n], 0, 0, 0);
        acc[m][n] = __builtin_amdgcn_mfma_f32_16x16x32_bf16(ah[m], bl[n], acc[m][n], 0, 0, 0);
        acc[m][n] = __builtin_amdgcn_mfma_f32_16x16x32_bf16(al[m], bh[n], acc[m][n], 0, 0, 0);
      }
  }

  float* Sb = S + (size_t)b * LQ * LKV;
#pragma unroll
  for (int m = 0; m < 4; ++m) {
    int row0 = ti * 128 + wr + m * 16 + ((lane >> 4) << 2);
#pragma unroll
    for (int n = 0; n < 4; ++n) {
      int col = tj * 128 + wc + n * 16 + (lane & 15);
#pragma unroll
      for (int j = 0; j < 4; ++j)
        Sb[(size_t)(row0 + j) * LKV + col] = acc[m][n][j];
    }
  }
}

__global__ __launch_bounds__(256) void softmax_kernel(float* __restrict__ S)
{
  __shared__ float redmax[4], redsum[4];
  const int tid = threadIdx.x;
  float* p = S + (size_t)blockIdx.x * LKV;

  f4 v = *(const f4*)(p + tid * 4);
  float mx = fmaxf(fmaxf(v[0], v[1]), fmaxf(v[2], v[3]));
#pragma unroll
  for (int off = 32; off >= 1; off >>= 1)
    mx = fmaxf(mx, __shfl_xor(mx, off));
  if ((tid & 63) == 0) redmax[tid >> 6] = mx;
  __syncthreads();
  mx = fmaxf(fmaxf(redmax[0], redmax[1]), fmaxf(redmax[2], redmax[3]));

  f4 e;
#pragma unroll
  for (int u = 0; u < 4; ++u) e[u] = __expf(v[u] - mx);
  float sm = e[0] + e[1] + e[2] + e[3];
#pragma unroll
  for (int off = 32; off >= 1; off >>= 1)
    sm += __shfl_xor(sm, off);
  if ((tid & 63) == 0) redsum[tid >> 6] = sm;
  __syncthreads();
  sm = redsum[0] + redsum[1] + redsum[2] + redsum[3];

  float inv = 1.0f / sm;
  f4 o = { e[0] * inv, e[1] * inv, e[2] * inv, e[3] * inv };
  *(f4*)(p + tid * 4) = o;
}

__global__ __launch_bounds__(256) void kvt_prep_kernel(const float* __restrict__ KV,
                                                       unsigned short* __restrict__ KVT)
{
  __shared__ unsigned short T[64][72];
  const int b  = blockIdx.z;
  const int tk = blockIdx.y;
  const int td = blockIdx.x;
  const int tid = threadIdx.x;

#pragma unroll
  for (int i = 0; i < 4; ++i) {
    int idx = tid + i * 256;
    int r   = idx >> 4;
    int c4  = (idx & 15) << 2;
    f4 v = *(const f4*)(KV + ((size_t)b * LKV + tk * 64 + r) * DD + td * 64 + c4);
    u16x4 h;
#pragma unroll
    for (int u = 0; u < 4; ++u) h[u] = f2bf(v[u]);
    *(u16x4*)&T[r][c4] = h;
  }
  __syncthreads();

#pragma unroll
  for (int i = 0; i < 4; ++i) {
    int idx = tid + i * 256;
    int c   = idx >> 4;
    int r4  = (idx & 15) << 2;
    u16x4 w = { T[r4][c], T[r4 + 1][c], T[r4 + 2][c], T[r4 + 3][c] };
    *(u16x4*)(KVT + ((size_t)b * DD + td * 64 + c) * LKV + tk * 64 + r4) = w;
  }
}

__global__ __launch_bounds__(512) void gemm_av2_kernel(const float* __restrict__ A,
                                                       const unsigned short* __restrict__ KVT,
                                                       float* __restrict__ O)
{
  __shared__ unsigned short Asm[128][72];
  __shared__ unsigned short Bsm[256 * 64];
  const int b  = blockIdx.z;
  const int mi = blockIdx.y;
  const int nj = blockIdx.x;
  const int tid  = threadIdx.x;
  const int lane = tid & 63;
  const int wid  = tid >> 6;
  const int wr = (wid >> 2) * 64;
  const int wc = (wid & 3) * 64;

  const float* Ab = A + (size_t)b * LQ * LKV + (size_t)mi * 128 * LKV;
  const unsigned short* Bb = KVT + ((size_t)b * DD + nj * 256) * LKV;

  f32x4 acc[4][4] = {};

  for (int ks = 0; ks < LKV; ks += 64) {
    __syncthreads();
#pragma unroll
    for (int i = 0; i < 4; ++i) {
      int idx = tid + i * 512;
      int r   = idx >> 4;
      int k4  = (idx & 15) << 2;
      f4 v = *(const f4*)(Ab + (size_t)r * LKV + ks + k4);
      u16x4 h;
#pragma unroll
      for (int u = 0; u < 4; ++u) h[u] = f2bf(v[u]);
      *(u16x4*)&Asm[r][k4] = h;
    }
#pragma unroll
    for (int c = 0; c < 4; ++c) {
      int cc = wid * 4 + c;
      int dd = cc * 8 + (lane >> 3);
      int ss = (lane & 7) ^ (dd & 7);
      const unsigned short* g = Bb + (size_t)dd * LKV + ks + ss * 8;
      gload16(g, &Bsm[cc * 512]);
    }
    __syncthreads();

#pragma unroll
    for (int kk = 0; kk < 64; kk += 32) {
      const int kf = kk + ((lane >> 4) << 3);
      const int cl = kf >> 3;
      bf16x8 af[4], bfv[4];
#pragma unroll
      for (int m = 0; m < 4; ++m)
        af[m] = *(const bf16x8*)&Asm[wr + m * 16 + (lane & 15)][kf];
#pragma unroll
      for (int n = 0; n < 4; ++n) {
        int dd = wc + n * 16 + (lane & 15);
        int sp = cl ^ (dd & 7);
        bfv[n] = *(const bf16x8*)&Bsm[dd * 64 + sp * 8];
      }
#pragma unroll
      for (int m = 0; m < 4; ++m)
#pragma unroll
        for (int n = 0; n < 4; ++n)
          acc[m][n] = __builtin_amdgcn_mfma_f32_16x16x32_bf16(af[m], bfv[n], acc[m][n], 0, 0, 0);
    }
  }

  float* Ob = O + (size_t)b * LQ * DD;
#pragma unroll
  for (int m = 0; m < 4; ++m) {
    int row0 = mi * 128 + wr + m * 16 + ((lane >> 4) << 2);
#pragma unroll
    for (int n = 0; n < 4; ++n) {
      int col = nj * 256 + wc + n * 16 + (lane & 15);
#pragma unroll
      for (int j = 0; j < 4; ++j)
        Ob[(size_t)(row0 + j) * DD + col] = acc[m][n][j];
    }
  }
}

__global__ __launch_bounds__(256) void gemm_av_kernel(const float* __restrict__ A,
                                                      const float* __restrict__ KV,
                                                      float* __restrict__ O)
{
  __shared__ unsigned short Ab[128][PAD], Bt[128][PAD];
  const int b  = blockIdx.z;
  const int mi = blockIdx.y;
  const int nj = blockIdx.x;
  const int tid  = threadIdx.x;
  const int lane = tid & 63;
  const int wid  = tid >> 6;
  const int wr = (wid >> 1) * 64;
  const int wc = (wid & 1) * 64;

  const float* Arow = A  + (size_t)b * LQ * LKV + (size_t)mi * 128 * LKV;
  const float* Kb   = KV + (size_t)b * LKV * DD;

  f32x4 acc[4][4] = {};

  for (int ks = 0; ks < LKV; ks += 32) {
    __syncthreads();
#pragma unroll
    for (int i = 0; i < 4; ++i) {
      int idx = tid + i * 256;
      {
        int r  = idx >> 3;
        int k4 = (idx & 7) << 2;
        f4 av = *(const f4*)(Arow + (size_t)r * LKV + ks + k4);
        u16x4 h;
#pragma unroll
        for (int u = 0; u < 4; ++u) h[u] = f2bf(av[u]);
        *(u16x4*)&Ab[r][k4] = h;
      }
      {
        int kr = idx >> 5;
        int c4 = (idx & 31) << 2;
        f4 kv = *(const f4*)(Kb + (size_t)(ks + kr) * DD + nj * 128 + c4);
        unsigned short hv[4];
#pragma unroll
        for (int u = 0; u < 4; ++u) hv[u] = f2bf(kv[u]);
#pragma unroll
        for (int u = 0; u < 4; ++u) {
          int uu = (u + kr) & 3;
          Bt[c4 + uu][kr] = hv[uu];
        }
      }
    }
    __syncthreads();

    const int kf = (lane >> 4) << 3;
    bf16x8 af[4], bfv[4];
#pragma unroll
    for (int m = 0; m < 4; ++m)
      af[m] = *(const bf16x8*)&Ab[wr + m * 16 + (lane & 15)][kf];
#pragma unroll
    for (int n = 0; n < 4; ++n)
      bfv[n] = *(const bf16x8*)&Bt[wc + n * 16 + (lane & 15)][kf];
#pragma unroll
    for (int m = 0; m < 4; ++m)
#pragma unroll
      for (int n = 0; n < 4; ++n)
        acc[m][n] = __builtin_amdgcn_mfma_f32_16x16x32_bf16(af[m], bfv[n], acc[m][n], 0, 0, 0);
  }

  float* Ob = O + (size_t)b * LQ * DD;
#pragma unroll
  for (int m = 0; m < 4; ++m) {
    int row0 = mi * 128 + wr + m * 16 + ((lane >> 4) << 2);
#pragma unroll
    for (int n = 0; n < 4; ++n) {
      int col = nj * 128 + wc + n * 16 + (lane & 15);
#pragma unroll
      for (int j = 0; j < 4; ++j)
        Ob[(size_t)(row0 + j) * DD + col] = acc[m][n][j];
    }
  }
}

// ---------------------------------------------------------------------------
extern "C" void kernel_launch(void* const* d_in, const int* in_sizes, int n_in,
                              void* d_out, int out_size, void* d_ws, size_t ws_size,
                              hipStream_t stream) {
  const float* Q  = (const float*)d_in[0];
  const float* KV = (const float*)d_in[1];
  float* out  = (float*)d_out;                       // O region (B*LQ*D)
  float* attn = out + (size_t)NB * LQ * DD;          // attn region (B*LQ*LKV)

  const size_t NQ  = (size_t)NB * LQ * DD;                    // 16.78M elems
  const size_t big_bytes = 5 * NQ * sizeof(unsigned short);   // 167.8 MB
  const size_t kvt_bytes = NQ * sizeof(unsigned short);       // 33.5 MB

  if (ws_size >= big_bytes) {
    unsigned short* Qh  = (unsigned short*)d_ws;
    unsigned short* Qlo = Qh  + NQ;
    unsigned short* Kh  = Qlo + NQ;
    unsigned short* Kl  = Kh  + NQ;
    unsigned short* KVT = Kl  + NQ;
    // Partial stats live temporarily in the (not-yet-written) O region.
    float* Pmax = out;                     // NROWS*16 floats
    float* Psum = out + (size_t)NROWS * 16;
    // Row stats overlay the Kh region (dead after gemm_qk8; rewritten by
    // prep_all on every replay, so no cross-call state survives).
    float* Mrow = (float*)Kh;
    float* Invr = Mrow + NROWS;

    prep_all_kernel<<<dim3(DD / 64, LKV / 64, NB), 256, 0, stream>>>(Q, KV, Qh, Qlo, Kh, Kl, KVT);
    gemm_qk8_kernel<<<dim3(2048), 256, 0, stream>>>(Qh, Qlo, Kh, Kl, attn, Pmax, Psum);
    reduce_stats_kernel<<<NROWS / 256, 256, 0, stream>>>(Pmax, Psum, Mrow, Invr);
    gemm_av7_kernel<<<dim3(256), 1024, 0, stream>>>(attn, KVT, Mrow, Invr, out);
  } else if (ws_size >= kvt_bytes) {
    unsigned short* KVT = (unsigned short*)d_ws;
    gemm_qk_kernel<<<dim3(64, NB), 256, 0, stream>>>(Q, KV, attn);
    kvt_prep_kernel<<<dim3(DD / 64, LKV / 64, NB), 256, 0, stream>>>(KV, KVT);
    softmax_kernel<<<dim3(NB * LQ), 256, 0, stream>>>(attn);
    gemm_av2_kernel<<<dim3(DD / 256, LQ / 128, NB), 512, 0, stream>>>(attn, KVT, out);
  } else {
    gemm_qk_kernel<<<dim3(64, NB), 256, 0, stream>>>(Q, KV, attn);
    softmax_kernel<<<dim3(NB * LQ), 256, 0, stream>>>(attn);
    gemm_av_kernel<<<dim3(DD / 128, LQ / 128, NB), 256, 0, stream>>>(attn, KV, out);
  }
}

// Round 10
// 296.329 us; speedup vs baseline: 1.4763x; 1.4763x over previous
//
#include <hip/hip_runtime.h>

// Problem: B=32, LQ=1024, LKV=1024, D=512, fp32.
// out = [output (B*LQ*D), attn (B*LQ*LKV)] concatenated, fp32.

constexpr int NB  = 32;
constexpr int LQ  = 1024;
constexpr int LKV = 1024;
constexpr int DD  = 512;
constexpr int NROWS = NB * LQ;   // 32768 score rows

typedef __attribute__((ext_vector_type(4))) float f4;
typedef __attribute__((ext_vector_type(4))) float f32x4;
typedef __attribute__((ext_vector_type(4))) unsigned short u16x4;
typedef __attribute__((ext_vector_type(8))) __bf16 bf16x8;

__device__ __forceinline__ unsigned short f2bf(float x) {
  unsigned u = __builtin_bit_cast(unsigned, x);
  unsigned r = u + 0x7FFFu + ((u >> 16) & 1u);   // round-to-nearest-even
  return (unsigned short)(r >> 16);
}
__device__ __forceinline__ float bf2f(unsigned short h) {
  unsigned u = ((unsigned)h) << 16;
  return __builtin_bit_cast(float, u);
}

__device__ __forceinline__ void gload16(const void* g, void* l) {
  __builtin_amdgcn_global_load_lds((const __attribute__((address_space(1))) unsigned int*)g,
                                   (__attribute__((address_space(3))) unsigned int*)l,
                                   16, 0, 0);
}

constexpr int PAD = 40;

// ---------------------------------------------------------------------------
// Prep (merged): Q -> Qh,Ql ; KV -> Kh,Kl ([kv][d]) and KVT ([d][kv], hi only)
// ---------------------------------------------------------------------------
__global__ __launch_bounds__(256) void prep_all_kernel(const float* __restrict__ Q,
                                                       const float* __restrict__ KV,
                                                       unsigned short* __restrict__ Qh,
                                                       unsigned short* __restrict__ Ql,
                                                       unsigned short* __restrict__ Kh,
                                                       unsigned short* __restrict__ Kl,
                                                       unsigned short* __restrict__ KVT)
{
  __shared__ unsigned short T[64][72];
  const int b  = blockIdx.z;
  const int tk = blockIdx.y;   // lq/kv tile (64), 0..15
  const int td = blockIdx.x;   // d tile (64), 0..7
  const int tid = threadIdx.x;

#pragma unroll
  for (int i = 0; i < 4; ++i) {
    int idx = tid + i * 256;
    int r   = idx >> 4;
    int c4  = (idx & 15) << 2;
    size_t goff = ((size_t)b * LKV + tk * 64 + r) * DD + td * 64 + c4;
    f4 v = *(const f4*)(KV + goff);
    u16x4 h, l;
#pragma unroll
    for (int u = 0; u < 4; ++u) {
      h[u] = f2bf(v[u]);
      l[u] = f2bf(v[u] - bf2f(h[u]));
    }
    *(u16x4*)&T[r][c4] = h;
    *(u16x4*)(Kh + goff) = h;
    *(u16x4*)(Kl + goff) = l;

    f4 q = *(const f4*)(Q + goff);
    u16x4 qh, ql;
#pragma unroll
    for (int u = 0; u < 4; ++u) {
      qh[u] = f2bf(q[u]);
      ql[u] = f2bf(q[u] - bf2f(qh[u]));
    }
    *(u16x4*)(Qh + goff) = qh;
    *(u16x4*)(Ql + goff) = ql;
  }
  __syncthreads();

#pragma unroll
  for (int i = 0; i < 4; ++i) {
    int idx = tid + i * 256;
    int c   = idx >> 4;                 // d row 0..63
    int r4  = (idx & 15) << 2;          // kv col
    u16x4 w = { T[r4][c], T[r4 + 1][c], T[r4 + 2][c], T[r4 + 3][c] };
    *(u16x4*)(KVT + ((size_t)b * DD + td * 64 + c) * LKV + tk * 64 + r4) = w;
  }
}

// ---------------------------------------------------------------------------
// Kernel 1: S = Q@KV^T (split-bf16, 3 MFMA) + partial softmax stats.
// EXACTLY round-4/5's best-measured qk4 structure (BK=64 single-buffer,
// 2 barriers per K-step, gload_lds + chunk swizzle, 143us), with ONE change:
// bijective XCD-aware block swizzle (round-8 evidence: FETCH 295->65 MB).
// ---------------------------------------------------------------------------
__global__ __launch_bounds__(256) void gemm_qk9_kernel(const unsigned short* __restrict__ Qh,
                                                       const unsigned short* __restrict__ Ql,
                                                       const unsigned short* __restrict__ Kh,
                                                       const unsigned short* __restrict__ Kl,
                                                       float* __restrict__ S,
                                                       float* __restrict__ Pmax,
                                                       float* __restrict__ Psum)
{
  __shared__ unsigned short SM[4][128 * 64];   // 64 KB, linear + swizzled
  // XCD swizzle (nwg=2048, %8==0 -> bijective): each XCD gets a contiguous
  // logical range (4 batches -> Q/K panels ~L2-resident per XCD).
  const int n       = blockIdx.x;              // 0..2047
  const int logical = (n & 7) * 256 + (n >> 3);
  const int b   = logical >> 6;
  const int t   = logical & 63;
  const int ti  = t >> 3;
  const int tj  = t & 7;
  const int tid  = threadIdx.x;
  const int lane = tid & 63;
  const int wid  = tid >> 6;            // 0..3
  const int wr = (wid >> 1) * 64;
  const int wc = (wid & 1) * 64;

  const size_t qo = ((size_t)b * LQ  + ti * 128) * DD;
  const size_t ko = ((size_t)b * LKV + tj * 128) * DD;
  const unsigned short* tb =
      (wid == 0) ? Qh + qo : (wid == 1) ? Ql + qo : (wid == 2) ? Kh + ko : Kl + ko;

  const int lrow = lane >> 3;
  const int ss   = (lane & 7) ^ lrow;

  f32x4 acc[4][4] = {};

  for (int ks = 0; ks < DD; ks += 64) {
    __syncthreads();
#pragma unroll
    for (int i = 0; i < 16; ++i) {
      const unsigned short* g = tb + (size_t)(i * 8 + lrow) * DD + ks + ss * 8;
      gload16(g, &SM[wid][i * 512]);
    }
    __syncthreads();

#pragma unroll
    for (int kk = 0; kk < 64; kk += 32) {
      const int cl  = (kk + ((lane >> 4) << 3)) >> 3;
      const int sp8 = (cl ^ (lane & 7)) * 8;
      bf16x8 ah[4], al[4], bh[4], bl[4];
#pragma unroll
      for (int m = 0; m < 4; ++m) {
        int r = wr + m * 16 + (lane & 15);
        ah[m] = *(const bf16x8*)&SM[0][r * 64 + sp8];
        al[m] = *(const bf16x8*)&SM[1][r * 64 + sp8];
      }
#pragma unroll
      for (int nn = 0; nn < 4; ++nn) {
        int r = wc + nn * 16 + (lane & 15);
        bh[nn] = *(const bf16x8*)&SM[2][r * 64 + sp8];
        bl[nn] = *(const bf16x8*)&SM[3][r * 64 + sp8];
      }
#pragma unroll
      for (int m = 0; m < 4; ++m)
#pragma unroll
        for (int nn = 0; nn < 4; ++nn)
          acc[m][nn] = __builtin_amdgcn_mfma_f32_16x16x32_bf16(ah[m], bh[nn], acc[m][nn], 0, 0, 0);
#pragma unroll
      for (int m = 0; m < 4; ++m)
#pragma unroll
        for (int nn = 0; nn < 4; ++nn)
          acc[m][nn] = __builtin_amdgcn_mfma_f32_16x16x32_bf16(ah[m], bl[nn], acc[m][nn], 0, 0, 0);
#pragma unroll
      for (int m = 0; m < 4; ++m)
#pragma unroll
        for (int nn = 0; nn < 4; ++nn)
          acc[m][nn] = __builtin_amdgcn_mfma_f32_16x16x32_bf16(al[m], bh[nn], acc[m][nn], 0, 0, 0);
    }
  }

  // ---- store raw scores ----
  float* Sb = S + (size_t)b * LQ * LKV;
#pragma unroll
  for (int m = 0; m < 4; ++m) {
    int row0 = ti * 128 + wr + m * 16 + ((lane >> 4) << 2);
#pragma unroll
    for (int nn = 0; nn < 4; ++nn) {
      int col = tj * 128 + wc + nn * 16 + (lane & 15);
#pragma unroll
      for (int j = 0; j < 4; ++j)
        Sb[(size_t)(row0 + j) * LKV + col] = acc[m][nn][j];
    }
  }

  // ---- per-row partial stats over this wave's 64 cols ----
  const int g16  = lane >> 4;
  const int l16  = lane & 15;
  const int wcid = wc >> 6;   // 0 or 1
#pragma unroll
  for (int m = 0; m < 4; ++m) {
#pragma unroll
    for (int j = 0; j < 4; ++j) {
      float rm = fmaxf(fmaxf(acc[m][0][j], acc[m][1][j]), fmaxf(acc[m][2][j], acc[m][3][j]));
#pragma unroll
      for (int off = 8; off >= 1; off >>= 1)
        rm = fmaxf(rm, __shfl_xor(rm, off));
      float se = 0.f;
#pragma unroll
      for (int nn = 0; nn < 4; ++nn)
        se += __expf(acc[m][nn][j] - rm);
#pragma unroll
      for (int off = 8; off >= 1; off >>= 1)
        se += __shfl_xor(se, off);
      if (l16 == 0) {
        int row  = ti * 128 + wr + m * 16 + g16 * 4 + j;
        size_t p = ((size_t)b * LQ + row) * 16 + tj * 2 + wcid;
        Pmax[p] = rm;
        Psum[p] = se;
      }
    }
  }
}

// ---------------------------------------------------------------------------
// Reduce: 16 partials/row -> M[row], Inv[row] = 1/sum
// ---------------------------------------------------------------------------
__global__ __launch_bounds__(256) void reduce_stats_kernel(const float* __restrict__ Pmax,
                                                           const float* __restrict__ Psum,
                                                           float* __restrict__ M,
                                                           float* __restrict__ Inv)
{
  int row = blockIdx.x * 256 + threadIdx.x;
  const float* pm = Pmax + (size_t)row * 16;
  const float* ps = Psum + (size_t)row * 16;
  float mx = pm[0];
#pragma unroll
  for (int i = 1; i < 16; ++i) mx = fmaxf(mx, pm[i]);
  float s = 0.f;
#pragma unroll
  for (int i = 0; i < 16; ++i) s += ps[i] * __expf(pm[i] - mx);
  M[row]   = mx;
  Inv[row] = 1.0f / s;
}

// ---------------------------------------------------------------------------
// Kernel 3: fused normalize + O = softmax(S) @ KV.
// BM=128, BN=512, BK=64, 1024 threads = 16 waves (4x4). XCD swizzle.
// (identical to round 5/7 measured ~80-84us)
// ---------------------------------------------------------------------------
__global__ __launch_bounds__(1024, 4) void gemm_av7_kernel(float* __restrict__ Sio,
                                                           const unsigned short* __restrict__ KVT,
                                                           const float* __restrict__ Mrow,
                                                           const float* __restrict__ Invr,
                                                           float* __restrict__ O)
{
  __shared__ unsigned short Asm[128][72];      // 18 KB padded
  __shared__ unsigned short Bsm[512 * 64];     // 64 KB linear, chunk-swizzled
  __shared__ float Ms[128], Is[128];
  const int n       = blockIdx.x;              // 0..255
  const int logical = (n & 7) * 32 + (n >> 3);
  const int b  = logical >> 3;
  const int mi = logical & 7;
  const int tid  = threadIdx.x;       // 0..1023
  const int lane = tid & 63;
  const int wid  = tid >> 6;          // 0..15
  const int wr  = (wid >> 2) * 32;    // wave row base: 0,32,64,96
  const int wcb = (wid & 3) * 128;    // wave col base: 0,128,256,384

  float* Sb = Sio + ((size_t)b * LQ + mi * 128) * LKV;
  const unsigned short* Bb = KVT + (size_t)b * DD * LKV;

  if (tid < 128) {
    int gr = b * LQ + mi * 128 + tid;
    Ms[tid] = Mrow[gr];
    Is[tid] = Invr[gr];
  }

  const int lr8 = lane >> 3;
  const int ssw = (lane & 7) ^ lr8;    // pre-swizzled global slot for staging

  f32x4 acc[2][8] = {};

  for (int ks = 0; ks < LKV; ks += 64) {
    __syncthreads();   // first iter also publishes Ms/Is
    // ---- A: 128 x 64 raw S -> p=exp(s-M)*Inv -> attn (in place) + bf16 LDS
#pragma unroll
    for (int i = 0; i < 2; ++i) {
      int idx = tid + i * 1024;        // 0..2047
      int r   = idx >> 4;              // 0..127
      int k4  = (idx & 15) << 2;       // 0,4,..,60
      float* ap = Sb + (size_t)r * LKV + ks + k4;
      f4 v = *(const f4*)ap;
      float mr = Ms[r], ir = Is[r];
      f4 p; u16x4 h;
#pragma unroll
      for (int u = 0; u < 4; ++u) {
        p[u] = __expf(v[u] - mr) * ir;
        h[u] = f2bf(p[u]);
      }
      *(f4*)ap = p;
      *(u16x4*)&Asm[r][k4] = h;
    }
    // ---- B: 512 d-rows x 64 kv via gload_lds (4 chunks/wave, 64 total) ----
#pragma unroll
    for (int c = 0; c < 4; ++c) {
      int cc = wid * 4 + c;                    // 0..63
      int dd = cc * 8 + lr8;                   // 0..511
      const unsigned short* g = Bb + (size_t)dd * LKV + ks + ssw * 8;
      gload16(g, &Bsm[cc * 512]);
    }
    __syncthreads();

    // ---- compute: 2 k-subtiles of 32 ----
#pragma unroll
    for (int kk = 0; kk < 64; kk += 32) {
      const int kf = kk + ((lane >> 4) << 3);
      const int cl = kf >> 3;
      bf16x8 af[2];
#pragma unroll
      for (int m = 0; m < 2; ++m)
        af[m] = *(const bf16x8*)&Asm[wr + m * 16 + (lane & 15)][kf];
#pragma unroll
      for (int h = 0; h < 2; ++h) {
        bf16x8 bfv[4];
#pragma unroll
        for (int nn = 0; nn < 4; ++nn) {
          int dd = wcb + (h * 4 + nn) * 16 + (lane & 15);
          int sp = cl ^ (dd & 7);
          bfv[nn] = *(const bf16x8*)&Bsm[dd * 64 + sp * 8];
        }
#pragma unroll
        for (int m = 0; m < 2; ++m)
#pragma unroll
          for (int nn = 0; nn < 4; ++nn)
            acc[m][h * 4 + nn] =
                __builtin_amdgcn_mfma_f32_16x16x32_bf16(af[m], bfv[nn], acc[m][h * 4 + nn], 0, 0, 0);
      }
    }
  }

  float* Ob = O + ((size_t)b * LQ + mi * 128) * DD;
#pragma unroll
  for (int m = 0; m < 2; ++m) {
    int r0 = wr + m * 16 + ((lane >> 4) << 2);
#pragma unroll
    for (int nn = 0; nn < 8; ++nn) {
      int col = wcb + nn * 16 + (lane & 15);
#pragma unroll
      for (int j = 0; j < 4; ++j)
        Ob[(size_t)(r0 + j) * DD + col] = acc[m][nn][j];
    }
  }
}

// ===========================================================================
// Fallback kernels (smaller ws paths) — unchanged.
// ===========================================================================
__global__ __launch_bounds__(256) void gemm_qk_kernel(const float* __restrict__ Q,
                                                      const float* __restrict__ KV,
                                                      float* __restrict__ S)
{
  __shared__ unsigned short Ah[128][PAD], Al[128][PAD], Bh[128][PAD], Bl[128][PAD];
  const int b   = blockIdx.y;
  const int ti  = blockIdx.x >> 3;
  const int tj  = blockIdx.x & 7;
  const int tid  = threadIdx.x;
  const int lane = tid & 63;
  const int wid  = tid >> 6;
  const int wr = (wid >> 1) * 64;
  const int wc = (wid & 1) * 64;

  const float* Qb = Q  + (size_t)b * LQ  * DD + (size_t)ti * 128 * DD;
  const float* Kb = KV + (size_t)b * LKV * DD + (size_t)tj * 128 * DD;

  f32x4 acc[4][4] = {};

  for (int ks = 0; ks < DD; ks += 32) {
    __syncthreads();
#pragma unroll
    for (int i = 0; i < 4; ++i) {
      int idx = tid + i * 256;
      int r   = idx >> 3;
      int k4  = (idx & 7) << 2;
      f4 qa = *(const f4*)(Qb + (size_t)r * DD + ks + k4);
      f4 ka = *(const f4*)(Kb + (size_t)r * DD + ks + k4);
      u16x4 qh, ql, kh, kl;
#pragma unroll
      for (int u = 0; u < 4; ++u) {
        unsigned short h = f2bf(qa[u]);
        qh[u] = h;  ql[u] = f2bf(qa[u] - bf2f(h));
        unsigned short h2 = f2bf(ka[u]);
        kh[u] = h2; kl[u] = f2bf(ka[u] - bf2f(h2));
      }
      *(u16x4*)&Ah[r][k4] = qh;  *(u16x4*)&Al[r][k4] = ql;
      *(u16x4*)&Bh[r][k4] = kh;  *(u16x4*)&Bl[r][k4] = kl;
    }
    __syncthreads();

    const int kf = (lane >> 4) << 3;
    bf16x8 ah[4], al[4], bh[4], bl[4];
#pragma unroll
    for (int m = 0; m < 4; ++m) {
      int row = wr + m * 16 + (lane & 15);
      ah[m] = *(const bf16x8*)&Ah[row][kf];
      al[m] = *(const bf16x8*)&Al[row][kf];
    }
#pragma unroll
    for (int n = 0; n < 4; ++n) {
      int row = wc + n * 16 + (lane & 15);
      bh[n] = *(const bf16x8*)&Bh[row][kf];
      bl[n] = *(const bf16x8*)&Bl[row][kf];
    }
#pragma unroll
    for (int m = 0; m < 4; ++m)
#pragma unroll
      for (int n = 0; n < 4; ++n) {
        acc[m][n] = __builtin_amdgcn_mfma_f32_16x16x32_bf16(ah[m], bh[n], acc[m][n], 0, 0, 0);
        acc[m][n] = __builtin_amdgcn_mfma_f32_16x16x32_bf16(ah[m], bl[n], acc[m][n], 0, 0, 0);
        acc[m][n] = __builtin_amdgcn_mfma_f32_16x16x32_bf16(al[m], bh[n], acc[m][n], 0, 0, 0);
      }
  }

  float* Sb = S + (size_t)b * LQ * LKV;
#pragma unroll
  for (int m = 0; m < 4; ++m) {
    int row0 = ti * 128 + wr + m * 16 + ((lane >> 4) << 2);
#pragma unroll
    for (int n = 0; n < 4; ++n) {
      int col = tj * 128 + wc + n * 16 + (lane & 15);
#pragma unroll
      for (int j = 0; j < 4; ++j)
        Sb[(size_t)(row0 + j) * LKV + col] = acc[m][n][j];
    }
  }
}

__global__ __launch_bounds__(256) void softmax_kernel(float* __restrict__ S)
{
  __shared__ float redmax[4], redsum[4];
  const int tid = threadIdx.x;
  float* p = S + (size_t)blockIdx.x * LKV;

  f4 v = *(const f4*)(p + tid * 4);
  float mx = fmaxf(fmaxf(v[0], v[1]), fmaxf(v[2], v[3]));
#pragma unroll
  for (int off = 32; off >= 1; off >>= 1)
    mx = fmaxf(mx, __shfl_xor(mx, off));
  if ((tid & 63) == 0) redmax[tid >> 6] = mx;
  __syncthreads();
  mx = fmaxf(fmaxf(redmax[0], redmax[1]), fmaxf(redmax[2], redmax[3]));

  f4 e;
#pragma unroll
  for (int u = 0; u < 4; ++u) e[u] = __expf(v[u] - mx);
  float sm = e[0] + e[1] + e[2] + e[3];
#pragma unroll
  for (int off = 32; off >= 1; off >>= 1)
    sm += __shfl_xor(sm, off);
  if ((tid & 63) == 0) redsum[tid >> 6] = sm;
  __syncthreads();
  sm = redsum[0] + redsum[1] + redsum[2] + redsum[3];

  float inv = 1.0f / sm;
  f4 o = { e[0] * inv, e[1] * inv, e[2] * inv, e[3] * inv };
  *(f4*)(p + tid * 4) = o;
}

__global__ __launch_bounds__(256) void kvt_prep_kernel(const float* __restrict__ KV,
                                                       unsigned short* __restrict__ KVT)
{
  __shared__ unsigned short T[64][72];
  const int b  = blockIdx.z;
  const int tk = blockIdx.y;
  const int td = blockIdx.x;
  const int tid = threadIdx.x;

#pragma unroll
  for (int i = 0; i < 4; ++i) {
    int idx = tid + i * 256;
    int r   = idx >> 4;
    int c4  = (idx & 15) << 2;
    f4 v = *(const f4*)(KV + ((size_t)b * LKV + tk * 64 + r) * DD + td * 64 + c4);
    u16x4 h;
#pragma unroll
    for (int u = 0; u < 4; ++u) h[u] = f2bf(v[u]);
    *(u16x4*)&T[r][c4] = h;
  }
  __syncthreads();

#pragma unroll
  for (int i = 0; i < 4; ++i) {
    int idx = tid + i * 256;
    int c   = idx >> 4;
    int r4  = (idx & 15) << 2;
    u16x4 w = { T[r4][c], T[r4 + 1][c], T[r4 + 2][c], T[r4 + 3][c] };
    *(u16x4*)(KVT + ((size_t)b * DD + td * 64 + c) * LKV + tk * 64 + r4) = w;
  }
}

__global__ __launch_bounds__(512) void gemm_av2_kernel(const float* __restrict__ A,
                                                       const unsigned short* __restrict__ KVT,
                                                       float* __restrict__ O)
{
  __shared__ unsigned short Asm[128][72];
  __shared__ unsigned short Bsm[256 * 64];
  const int b  = blockIdx.z;
  const int mi = blockIdx.y;
  const int nj = blockIdx.x;
  const int tid  = threadIdx.x;
  const int lane = tid & 63;
  const int wid  = tid >> 6;
  const int wr = (wid >> 2) * 64;
  const int wc = (wid & 3) * 64;

  const float* Ab = A + (size_t)b * LQ * LKV + (size_t)mi * 128 * LKV;
  const unsigned short* Bb = KVT + ((size_t)b * DD + nj * 256) * LKV;

  f32x4 acc[4][4] = {};

  for (int ks = 0; ks < LKV; ks += 64) {
    __syncthreads();
#pragma unroll
    for (int i = 0; i < 4; ++i) {
      int idx = tid + i * 512;
      int r   = idx >> 4;
      int k4  = (idx & 15) << 2;
      f4 v = *(const f4*)(Ab + (size_t)r * LKV + ks + k4);
      u16x4 h;
#pragma unroll
      for (int u = 0; u < 4; ++u) h[u] = f2bf(v[u]);
      *(u16x4*)&Asm[r][k4] = h;
    }
#pragma unroll
    for (int c = 0; c < 4; ++c) {
      int cc = wid * 4 + c;
      int dd = cc * 8 + (lane >> 3);
      int ss = (lane & 7) ^ (dd & 7);
      const unsigned short* g = Bb + (size_t)dd * LKV + ks + ss * 8;
      gload16(g, &Bsm[cc * 512]);
    }
    __syncthreads();

#pragma unroll
    for (int kk = 0; kk < 64; kk += 32) {
      const int kf = kk + ((lane >> 4) << 3);
      const int cl = kf >> 3;
      bf16x8 af[4], bfv[4];
#pragma unroll
      for (int m = 0; m < 4; ++m)
        af[m] = *(const bf16x8*)&Asm[wr + m * 16 + (lane & 15)][kf];
#pragma unroll
      for (int n = 0; n < 4; ++n) {
        int dd = wc + n * 16 + (lane & 15);
        int sp = cl ^ (dd & 7);
        bfv[n] = *(const bf16x8*)&Bsm[dd * 64 + sp * 8];
      }
#pragma unroll
      for (int m = 0; m < 4; ++m)
#pragma unroll
        for (int n = 0; n < 4; ++n)
          acc[m][n] = __builtin_amdgcn_mfma_f32_16x16x32_bf16(af[m], bfv[n], acc[m][n], 0, 0, 0);
    }
  }

  float* Ob = O + (size_t)b * LQ * DD;
#pragma unroll
  for (int m = 0; m < 4; ++m) {
    int row0 = mi * 128 + wr + m * 16 + ((lane >> 4) << 2);
#pragma unroll
    for (int n = 0; n < 4; ++n) {
      int col = nj * 256 + wc + n * 16 + (lane & 15);
#pragma unroll
      for (int j = 0; j < 4; ++j)
        Ob[(size_t)(row0 + j) * DD + col] = acc[m][n][j];
    }
  }
}

__global__ __launch_bounds__(256) void gemm_av_kernel(const float* __restrict__ A,
                                                      const float* __restrict__ KV,
                                                      float* __restrict__ O)
{
  __shared__ unsigned short Ab[128][PAD], Bt[128][PAD];
  const int b  = blockIdx.z;
  const int mi = blockIdx.y;
  const int nj = blockIdx.x;
  const int tid  = threadIdx.x;
  const int lane = tid & 63;
  const int wid  = tid >> 6;
  const int wr = (wid >> 1) * 64;
  const int wc = (wid & 1) * 64;

  const float* Arow = A  + (size_t)b * LQ * LKV + (size_t)mi * 128 * LKV;
  const float* Kb   = KV + (size_t)b * LKV * DD;

  f32x4 acc[4][4] = {};

  for (int ks = 0; ks < LKV; ks += 32) {
    __syncthreads();
#pragma unroll
    for (int i = 0; i < 4; ++i) {
      int idx = tid + i * 256;
      {
        int r  = idx >> 3;
        int k4 = (idx & 7) << 2;
        f4 av = *(const f4*)(Arow + (size_t)r * LKV + ks + k4);
        u16x4 h;
#pragma unroll
        for (int u = 0; u < 4; ++u) h[u] = f2bf(av[u]);
        *(u16x4*)&Ab[r][k4] = h;
      }
      {
        int kr = idx >> 5;
        int c4 = (idx & 31) << 2;
        f4 kv = *(const f4*)(Kb + (size_t)(ks + kr) * DD + nj * 128 + c4);
        unsigned short hv[4];
#pragma unroll
        for (int u = 0; u < 4; ++u) hv[u] = f2bf(kv[u]);
#pragma unroll
        for (int u = 0; u < 4; ++u) {
          int uu = (u + kr) & 3;
          Bt[c4 + uu][kr] = hv[uu];
        }
      }
    }
    __syncthreads();

    const int kf = (lane >> 4) << 3;
    bf16x8 af[4], bfv[4];
#pragma unroll
    for (int m = 0; m < 4; ++m)
      af[m] = *(const bf16x8*)&Ab[wr + m * 16 + (lane & 15)][kf];
#pragma unroll
    for (int n = 0; n < 4; ++n)
      bfv[n] = *(const bf16x8*)&Bt[wc + n * 16 + (lane & 15)][kf];
#pragma unroll
    for (int m = 0; m < 4; ++m)
#pragma unroll
      for (int n = 0; n < 4; ++n)
        acc[m][n] = __builtin_amdgcn_mfma_f32_16x16x32_bf16(af[m], bfv[n], acc[m][n], 0, 0, 0);
  }

  float* Ob = O + (size_t)b * LQ * DD;
#pragma unroll
  for (int m = 0; m < 4; ++m) {
    int row0 = mi * 128 + wr + m * 16 + ((lane >> 4) << 2);
#pragma unroll
    for (int n = 0; n < 4; ++n) {
      int col = nj * 128 + wc + n * 16 + (lane & 15);
#pragma unroll
      for (int j = 0; j < 4; ++j)
        Ob[(size_t)(row0 + j) * DD + col] = acc[m][n][j];
    }
  }
}

// ---------------------------------------------------------------------------
extern "C" void kernel_launch(void* const* d_in, const int* in_sizes, int n_in,
                              void* d_out, int out_size, void* d_ws, size_t ws_size,
                              hipStream_t stream) {
  const float* Q  = (const float*)d_in[0];
  const float* KV = (const float*)d_in[1];
  float* out  = (float*)d_out;                       // O region (B*LQ*D)
  float* attn = out + (size_t)NB * LQ * DD;          // attn region (B*LQ*LKV)

  const size_t NQ  = (size_t)NB * LQ * DD;                    // 16.78M elems
  const size_t big_bytes = 5 * NQ * sizeof(unsigned short);   // 167.8 MB
  const size_t kvt_bytes = NQ * sizeof(unsigned short);       // 33.5 MB

  if (ws_size >= big_bytes) {
    unsigned short* Qh  = (unsigned short*)d_ws;
    unsigned short* Qlo = Qh  + NQ;
    unsigned short* Kh  = Qlo + NQ;
    unsigned short* Kl  = Kh  + NQ;
    unsigned short* KVT = Kl  + NQ;
    // Partial stats live temporarily in the (not-yet-written) O region.
    float* Pmax = out;                     // NROWS*16 floats
    float* Psum = out + (size_t)NROWS * 16;
    // Row stats overlay the Kh region (dead after gemm_qk9; rewritten by
    // prep_all on every replay, so no cross-call state survives).
    float* Mrow = (float*)Kh;
    float* Invr = Mrow + NROWS;

    prep_all_kernel<<<dim3(DD / 64, LKV / 64, NB), 256, 0, stream>>>(Q, KV, Qh, Qlo, Kh, Kl, KVT);
    gemm_qk9_kernel<<<dim3(2048), 256, 0, stream>>>(Qh, Qlo, Kh, Kl, attn, Pmax, Psum);
    reduce_stats_kernel<<<NROWS / 256, 256, 0, stream>>>(Pmax, Psum, Mrow, Invr);
    gemm_av7_kernel<<<dim3(256), 1024, 0, stream>>>(attn, KVT, Mrow, Invr, out);
  } else if (ws_size >= kvt_bytes) {
    unsigned short* KVT = (unsigned short*)d_ws;
    gemm_qk_kernel<<<dim3(64, NB), 256, 0, stream>>>(Q, KV, attn);
    kvt_prep_kernel<<<dim3(DD / 64, LKV / 64, NB), 256, 0, stream>>>(KV, KVT);
    softmax_kernel<<<dim3(NB * LQ), 256, 0, stream>>>(attn);
    gemm_av2_kernel<<<dim3(DD / 256, LQ / 128, NB), 512, 0, stream>>>(attn, KVT, out);
  } else {
    gemm_qk_kernel<<<dim3(64, NB), 256, 0, stream>>>(Q, KV, attn);
    softmax_kernel<<<dim3(NB * LQ), 256, 0, stream>>>(attn);
    gemm_av_kernel<<<dim3(DD / 128, LQ / 128, NB), 256, 0, stream>>>(attn, KV, out);
  }
}